// Round 21
// baseline (775.547 us; speedup 1.0000x reference)
//
#include <hip/hip_runtime.h>
#include <hip/hip_bf16.h>
#include <stdint.h>

#define Bn   16
#define Nn   4096
#define Sn   1024
#define Kn   8
#define CINn 128
#define COUTn 256

typedef __attribute__((ext_vector_type(8))) short bf16x8;
typedef __attribute__((ext_vector_type(4))) float f32x4;
typedef unsigned short ushort;
typedef __attribute__((ext_vector_type(8))) unsigned short ushort8;

// Exact f32 squared distance, no FMA contraction: matches ((dx*dx+dy*dy)+dz*dz)
static __device__ __forceinline__ float sqdist(float ax, float ay, float az,
                                               float bx, float by, float bz) {
    float dx = __fsub_rn(ax, bx);
    float dy = __fsub_rn(ay, by);
    float dz = __fsub_rn(az, bz);
    return __fadd_rn(__fadd_rn(__fmul_rn(dx, dx), __fmul_rn(dy, dy)), __fmul_rn(dz, dz));
}

static __device__ __forceinline__ unsigned long long u64max(unsigned long long a,
                                                            unsigned long long b) {
    return a > b ? a : b;
}

// f32 -> bf16 bits, round-to-nearest-even (finite inputs)
static __device__ __forceinline__ ushort f2bf(float f) {
    unsigned x = __float_as_uint(f);
    unsigned r = x + 0x7FFFu + ((x >> 16) & 1u);
    return (ushort)(r >> 16);
}

// ---- Wave-wide f32 max via DPP ladder (controls r14-validated; VOP2 folds) -
template <int CTRL>
static __device__ __forceinline__ void dpp_fmax_lvl(int& x) {
    int o = __builtin_amdgcn_update_dpp(x, x, CTRL, 0xF, 0xF, false);
    float f = fmaxf(__int_as_float(x), __int_as_float(o));
    x = __float_as_int(f);
}
static __device__ __forceinline__ float wave_max_f32(float v) {
    int x = __float_as_int(v);
    dpp_fmax_lvl<0x111>(x);   // row_shr:1
    dpp_fmax_lvl<0x112>(x);   // row_shr:2
    dpp_fmax_lvl<0x114>(x);   // row_shr:4
    dpp_fmax_lvl<0x118>(x);   // row_shr:8
    dpp_fmax_lvl<0x142>(x);   // row_bcast:15
    dpp_fmax_lvl<0x143>(x);   // row_bcast:31
    return __int_as_float(__builtin_amdgcn_readlane(x, 63));
}

// ---- Wave-wide u32 min via DPP ladder (same controls) ----------------------
template <int CTRL>
static __device__ __forceinline__ void dpp_umin_lvl(int& x) {
    int o = __builtin_amdgcn_update_dpp(x, x, CTRL, 0xF, 0xF, false);
    unsigned a = (unsigned)x, b2 = (unsigned)o;
    x = (int)(a < b2 ? a : b2);
}
static __device__ __forceinline__ unsigned wave_min_u32(unsigned v) {
    int x = (int)v;
    dpp_umin_lvl<0x111>(x);
    dpp_umin_lvl<0x112>(x);
    dpp_umin_lvl<0x114>(x);
    dpp_umin_lvl<0x118>(x);
    dpp_umin_lvl<0x142>(x);
    dpp_umin_lvl<0x143>(x);
    return (unsigned)__builtin_amdgcn_readlane(x, 63);
}

// ---------------- Kernel: farthest point sampling ---------------------------
// Exact argmax/tie-break semantics (validated r6-r20 via output 0), argmax
// DEFERRED: loop does pure min-update; thread-max via fmaxf tree (exactly
// associative, no NaN, all >= 0); wave-max via f32 DPP; index recovered by
// equality scan (M is a bitwise copy of some dist[j]); smallest global index
// among ties via u32-min DPP; cross-wave via the validated u64-key gbuf max.
__global__ __launch_bounds__(256) void k_fps(const float* __restrict__ xyz,
                                             float* __restrict__ out_xyz) {
    __shared__ __align__(16) float xs[Nn], ys[Nn], zs[Nn];
    __shared__ __align__(16) unsigned long long gbuf[2][4];
    const int b = blockIdx.x;
    const int tid = threadIdx.x;
    const int wid = tid >> 6, lane = tid & 63;
    const float* base = xyz + (size_t)b * 3 * Nn;
    for (int i = tid; i < Nn; i += 256) {
        xs[i] = base[i];
        ys[i] = base[Nn + i];
        zs[i] = base[2 * Nn + i];
    }
    __syncthreads();
    float px[16], py[16], pz[16], dist[16];
#pragma unroll
    for (int j = 0; j < 16; ++j) {
        int p = tid + j * 256;
        px[j] = xs[p]; py[j] = ys[p]; pz[j] = zs[p];
        dist[j] = 3.402823466e+38f;   // FLT_MAX, matches jnp.finfo(f32).max
    }
    int last = 0;
    if (tid == 0) {
        out_xyz[(size_t)(b * Sn) * 3 + 0] = xs[0];
        out_xyz[(size_t)(b * Sn) * 3 + 1] = ys[0];
        out_xyz[(size_t)(b * Sn) * 3 + 2] = zs[0];
    }
    for (int s = 1; s < Sn; ++s) {
        const float cx = xs[last], cy = ys[last], cz = zs[last];
        // pure min update (no in-loop argmax tracking)
#pragma unroll
        for (int j = 0; j < 16; ++j) {
            float d = sqdist(px[j], py[j], pz[j], cx, cy, cz);
            dist[j] = fminf(dist[j], d);
        }
        // thread max via max3-friendly tree (exact: max is associative)
        float m0 = fmaxf(fmaxf(dist[0], dist[1]), dist[2]);
        float m1 = fmaxf(fmaxf(dist[3], dist[4]), dist[5]);
        float m2 = fmaxf(fmaxf(dist[6], dist[7]), dist[8]);
        float m3 = fmaxf(fmaxf(dist[9], dist[10]), dist[11]);
        float m4 = fmaxf(fmaxf(dist[12], dist[13]), dist[14]);
        float mv = fmaxf(fmaxf(fmaxf(m0, m1), fmaxf(m2, m3)),
                         fmaxf(m4, dist[15]));
        // wave max (all lanes receive M via readlane 63)
        const float M = wave_max_f32(mv);
        // index recovery: descending j scan -> smallest local j with ==M;
        // within a thread, smaller j == smaller global index (tid + j*256).
        unsigned gi = 0xFFFFFFFFu;
#pragma unroll
        for (int j = 15; j >= 0; --j)
            gi = (dist[j] == M) ? (unsigned)(tid + j * 256) : gi;
        // smallest global index among exact ties across the wave
        const unsigned gimin = wave_min_u32(gi);
        if (lane == 0)
            gbuf[s & 1][wid] = ((unsigned long long)__float_as_uint(M) << 32) |
                               (unsigned)(Nn - 1 - gimin);
        __syncthreads();
        const ulonglong2 g0 = *(const ulonglong2*)&gbuf[s & 1][0];
        const ulonglong2 g1 = *(const ulonglong2*)&gbuf[s & 1][2];
        const unsigned long long key = u64max(u64max(g0.x, g0.y), u64max(g1.x, g1.y));
        const int nl = Nn - 1 - (int)(unsigned)(key & 0xFFFFFFFFull);
        if (tid == 0) {
            out_xyz[(size_t)(b * Sn + s) * 3 + 0] = xs[nl];
            out_xyz[(size_t)(b * Sn + s) * 3 + 1] = ys[nl];
            out_xyz[(size_t)(b * Sn + s) * 3 + 2] = zs[nl];
        }
        last = nl;
        // double-buffered gbuf: no second barrier (validated r9-r20)
    }
}

// ---- Wave-local ball query (validated r10-r20 ballot logic) ----------------
static __device__ __forceinline__ void wave_ball(const float* __restrict__ base,
                                                 float cx, float cy, float cz,
                                                 int lane, int* bslot) {
    int cnt = 0;
    int idx0 = -1;
    for (int chunk = 0; chunk < Nn / 64; ++chunk) {
        const int p = chunk * 64 + lane;
        const float d2 = sqdist(base[p], base[Nn + p], base[2 * Nn + p], cx, cy, cz);
        const bool in = (d2 <= 0.04f);             // f32(0.2*0.2)
        const unsigned long long m = __ballot(in);
        if (m != 0ull) {
            if (idx0 < 0) idx0 = chunk * 64 + __builtin_ctzll(m);
            const int rank = cnt + __popcll(m & ((1ull << lane) - 1ull));
            if (in && rank < Kn)
                bslot[rank] = p;                    // ascending by construction
            cnt += __popcll(m);
            if (cnt >= Kn) break;                   // wave-uniform
        }
    }
    if (lane < Kn && lane >= cnt)                   // pad with first index
        bslot[lane] = idx0;
}

// ---- Fused ball + bf16-MFMA conv + BN + ReLU + maxK (r20 text, validated) --
__global__ __launch_bounds__(512) void k_feat(const float* __restrict__ xyz,
                                              const float* __restrict__ out_xyz,
                                              const float* __restrict__ feat,
                                              const float* __restrict__ conv_w,
                                              const float* __restrict__ conv_b,
                                              const float* __restrict__ bn_g,
                                              const float* __restrict__ bn_b,
                                              const float* __restrict__ bn_m,
                                              const float* __restrict__ bn_v,
                                              float* __restrict__ out_feat) {
    __shared__ __align__(16) ushort A_lds[64][136];   // [(c,k)][f] 17.4 KB
    __shared__ __align__(16) ushort Wc[COUTn][40];    // [o][f_local] 20.5 KB
    __shared__ int bidx[8][Kn];
    const int tid = threadIdx.x;
    const int wave = tid >> 6, lane = tid & 63;
    const int b  = blockIdx.x & 15;                 // XCD-grouped batches
    const int c0 = (blockIdx.x >> 4) * 8;
    const int bs = b * Sn + c0 + wave;

    // ball query (wave-local)
    const float* base = xyz + (size_t)b * 3 * Nn;
    const float cx = out_xyz[(size_t)bs * 3 + 0];
    const float cy = out_xyz[(size_t)bs * 3 + 1];
    const float cz = out_xyz[(size_t)bs * 3 + 2];
    wave_ball(base, cx, cy, cz, lane, &bidx[wave][0]);
    __syncthreads();   // bidx visible to all waves (A staging reads it)

    // stage A (once): thread: row r=tid>>3 (=(c<<3)|k), f-range (tid&7)*16..+15
    const float* fb = feat + (size_t)b * CINn * Nn;
    {
        const int r = tid >> 3, fo = tid & 7;
        const int pt = bidx[r >> 3][r & 7];
        ushort us[16];
#pragma unroll
        for (int i = 0; i < 16; ++i)
            us[i] = f2bf(fb[(size_t)(fo * 16 + i) * Nn + pt]);
        *(ushort8*)&A_lds[r][fo * 16]     = *(const ushort8*)&us[0];
        *(ushort8*)&A_lds[r][fo * 16 + 8] = *(const ushort8*)&us[8];
    }

    // W chunk prefetch (ks=0): thread: o=tid>>1, f-half (tid&1)*16
    const int wo = tid >> 1, wfh = tid & 1;
    float4 stgW[4];
    {
        const float4* src = (const float4*)(conv_w + (size_t)wo * CINn + wfh * 16);
#pragma unroll
        for (int i = 0; i < 4; ++i) stgW[i] = src[i];
    }

    const int mt = wave & 3;
    const int obase = (wave >> 2) * 128;
    f32x4 acc[8];
#pragma unroll
    for (int t = 0; t < 8; ++t) acc[t] = (f32x4){0.f, 0.f, 0.f, 0.f};

    const int arow = mt * 16 + (lane & 15);
    const int kgrp = (lane >> 4) * 8;

#pragma unroll
    for (int ks = 0; ks < 4; ++ks) {
        // park W chunk (16 bf16 per thread -> 2 b128 writes)
        {
            ushort us[16];
#pragma unroll
            for (int i = 0; i < 4; ++i) {
                us[i * 4 + 0] = f2bf(stgW[i].x);
                us[i * 4 + 1] = f2bf(stgW[i].y);
                us[i * 4 + 2] = f2bf(stgW[i].z);
                us[i * 4 + 3] = f2bf(stgW[i].w);
            }
            *(ushort8*)&Wc[wo][wfh * 16]     = *(const ushort8*)&us[0];
            *(ushort8*)&Wc[wo][wfh * 16 + 8] = *(const ushort8*)&us[8];
        }
        __syncthreads();   // Wc[ks] ready (iter 0: A_lds too)
        // prefetch next W chunk
        if (ks < 3) {
            const float4* src = (const float4*)(conv_w + (size_t)wo * CINn +
                                                (ks + 1) * 32 + wfh * 16);
#pragma unroll
            for (int i = 0; i < 4; ++i) stgW[i] = src[i];
        }
        // compute: one A-frag (reused), 8 n-tiles
        const bf16x8 a = *(const bf16x8*)&A_lds[arow][ks * 32 + kgrp];
#pragma unroll
        for (int t = 0; t < 8; ++t) {
            const int o = obase + t * 16 + (lane & 15);
            const bf16x8 bb = *(const bf16x8*)&Wc[o][kgrp];
            acc[t] = __builtin_amdgcn_mfma_f32_16x16x32_bf16(a, bb, acc[t], 0, 0, 0);
        }
        __syncthreads();   // compute done before Wc overwrite
    }

    // epilogue: literal bias+BN+ReLU per (k,o), then max over k.
    const int half = lane >> 4;                 // 0,1: center A; 2,3: center B
#pragma unroll
    for (int t = 0; t < 8; ++t) {
        const int o = obase + t * 16 + (lane & 15);
        const float bias = conv_b[o];
        const float g = bn_g[o], be = bn_b[o], mn = bn_m[o], vr = bn_v[o];
        const float inv = sqrtf(vr + 1e-5f);
        float m4 = -3.402823466e+38f;
#pragma unroll
        for (int i = 0; i < 4; ++i) {
            float z = acc[t][i] + bias;
            float y = g * (z - mn) / inv + be;
            y = fmaxf(y, 0.0f);                 // ReLU before max, literal order
            m4 = fmaxf(m4, y);
        }
        const float mo = __shfl_xor(m4, 16);    // merge k 0-3 with k 4-7
        const float mx = fmaxf(m4, mo);
        if (half == 0)
            out_feat[(size_t)(b * Sn + c0 + mt * 2) * COUTn + o] = mx;
        else if (half == 2)
            out_feat[(size_t)(b * Sn + c0 + mt * 2 + 1) * COUTn + o] = mx;
    }
}

extern "C" void kernel_launch(void* const* d_in, const int* in_sizes, int n_in,
                              void* d_out, int out_size, void* d_ws, size_t ws_size,
                              hipStream_t stream) {
    const float* xyz    = (const float*)d_in[0];
    const float* feat   = (const float*)d_in[1];
    const float* conv_w = (const float*)d_in[2];
    const float* conv_b = (const float*)d_in[3];
    const float* bn_g   = (const float*)d_in[4];
    const float* bn_b   = (const float*)d_in[5];
    const float* bn_m   = (const float*)d_in[6];
    const float* bn_v   = (const float*)d_in[7];

    float* out_xyz  = (float*)d_out;
    float* out_feat = out_xyz + (size_t)Bn * Sn * 3;

    // no workspace usage
    k_fps <<<dim3(Bn),           dim3(256), 0, stream>>>(xyz, out_xyz);
    k_feat<<<dim3(Bn * Sn / 8),  dim3(512), 0, stream>>>(xyz, out_xyz, feat,
                                                         conv_w, conv_b,
                                                         bn_g, bn_b, bn_m, bn_v,
                                                         out_feat);
}

// Round 22
// 709.397 us; speedup vs baseline: 1.0932x; 1.0932x over previous
//
#include <hip/hip_runtime.h>
#include <hip/hip_bf16.h>
#include <stdint.h>

#define Bn   16
#define Nn   4096
#define Sn   1024
#define Kn   8
#define CINn 128
#define COUTn 256

typedef __attribute__((ext_vector_type(8))) short bf16x8;
typedef __attribute__((ext_vector_type(4))) float f32x4;
typedef __attribute__((ext_vector_type(2))) float f32x2;
typedef unsigned short ushort;
typedef __attribute__((ext_vector_type(8))) unsigned short ushort8;

// Exact f32 squared distance, no FMA contraction: matches ((dx*dx+dy*dy)+dz*dz)
static __device__ __forceinline__ float sqdist(float ax, float ay, float az,
                                               float bx, float by, float bz) {
    float dx = __fsub_rn(ax, bx);
    float dy = __fsub_rn(ay, by);
    float dz = __fsub_rn(az, bz);
    return __fadd_rn(__fadd_rn(__fmul_rn(dx, dx), __fmul_rn(dy, dy)), __fmul_rn(dz, dz));
}

static __device__ __forceinline__ unsigned long long u64max(unsigned long long a,
                                                            unsigned long long b) {
    return a > b ? a : b;
}

// f32 -> bf16 bits, round-to-nearest-even (finite inputs)
static __device__ __forceinline__ ushort f2bf(float f) {
    unsigned x = __float_as_uint(f);
    unsigned r = x + 0x7FFFu + ((x >> 16) & 1u);
    return (ushort)(r >> 16);
}

// Wave-wide u64 max via DPP (VALU pipe, no LDS) — r14/r20-validated on HW.
template <int CTRL>
static __device__ __forceinline__ void dpp_max_level(int& lo, int& hi) {
    int olo = __builtin_amdgcn_update_dpp(lo, lo, CTRL, 0xF, 0xF, false);
    int ohi = __builtin_amdgcn_update_dpp(hi, hi, CTRL, 0xF, 0xF, false);
    unsigned long long o = ((unsigned long long)(unsigned)ohi << 32) | (unsigned)olo;
    unsigned long long k = ((unsigned long long)(unsigned)hi << 32) | (unsigned)lo;
    if (o > k) { lo = olo; hi = ohi; }
}

static __device__ __forceinline__ unsigned long long wave_max_u64(unsigned long long key) {
    int lo = (int)(unsigned)(key & 0xFFFFFFFFull);
    int hi = (int)(unsigned)(key >> 32);
    dpp_max_level<0x111>(lo, hi);   // row_shr:1
    dpp_max_level<0x112>(lo, hi);   // row_shr:2
    dpp_max_level<0x114>(lo, hi);   // row_shr:4
    dpp_max_level<0x118>(lo, hi);   // row_shr:8
    dpp_max_level<0x142>(lo, hi);   // row_bcast:15
    dpp_max_level<0x143>(lo, hi);   // row_bcast:31
    unsigned flo = (unsigned)__builtin_amdgcn_readlane(lo, 63);
    unsigned fhi = (unsigned)__builtin_amdgcn_readlane(hi, 63);
    return ((unsigned long long)fhi << 32) | flo;
}

// ---------------- Kernel: farthest point sampling ---------------------------
// r20 structure (in-loop argmax, u64 DPP ladder, double-buffered reduction,
// one barrier) with two mechanism-targeted changes:
//  (1) dist update in packed f32x2 (contract(off): element-wise sub/mul/add
//      have identical IEEE rounding to the scalar __f*_rn sequence);
//  (2) winner coords carried through the reduction: each lane speculatively
//      fetches its own candidate's coords (overlaps the DPP ladder), the
//      unique wave-winner lane writes {key}->kbuf and {x,y,z}->cbuf; after
//      the barrier all 6 LDS reads issue in ONE latency window and a cndmask
//      tree selects the coords — the serial xs[nl] lookup is eliminated.
// Argmax/tie-break semantics bitwise identical (keys globally unique).
__global__ __launch_bounds__(256) void k_fps(const float* __restrict__ xyz,
                                             float* __restrict__ out_xyz) {
#pragma clang fp contract(off)
    __shared__ __align__(16) float xs[Nn], ys[Nn], zs[Nn];
    __shared__ __align__(16) unsigned long long kbuf[2][4];
    __shared__ __align__(16) float4 cbuf[2][4];
    const int b = blockIdx.x;
    const int tid = threadIdx.x;
    const int wid = tid >> 6;
    const float* base = xyz + (size_t)b * 3 * Nn;
    for (int i = tid; i < Nn; i += 256) {
        xs[i] = base[i];
        ys[i] = base[Nn + i];
        zs[i] = base[2 * Nn + i];
    }
    __syncthreads();
    f32x2 px[8], py[8], pz[8], dist[8];
#pragma unroll
    for (int j = 0; j < 8; ++j) {
        const int p0 = tid + (2 * j) * 256, p1 = p0 + 256;
        px[j] = (f32x2){xs[p0], xs[p1]};
        py[j] = (f32x2){ys[p0], ys[p1]};
        pz[j] = (f32x2){zs[p0], zs[p1]};
        dist[j] = (f32x2){3.402823466e+38f, 3.402823466e+38f};  // FLT_MAX
    }
    float cx = xs[0], cy = ys[0], cz = zs[0];
    if (tid == 0) {
        out_xyz[(size_t)(b * Sn) * 3 + 0] = cx;
        out_xyz[(size_t)(b * Sn) * 3 + 1] = cy;
        out_xyz[(size_t)(b * Sn) * 3 + 2] = cz;
    }
    for (int s = 1; s < Sn; ++s) {
        const f32x2 cx2 = (f32x2){cx, cx};
        const f32x2 cy2 = (f32x2){cy, cy};
        const f32x2 cz2 = (f32x2){cz, cz};
        float mv = -1.0f; int mi = 0;
#pragma unroll
        for (int j = 0; j < 8; ++j) {
            f32x2 dx = px[j] - cx2;
            f32x2 dy = py[j] - cy2;
            f32x2 dz = pz[j] - cz2;
            f32x2 xx = dx * dx, yy = dy * dy, zz = dz * dz;
            f32x2 ss = (xx + yy) + zz;          // contract(off): no pk_fma
            const float n0 = fminf(dist[j].x, ss.x);
            const float n1 = fminf(dist[j].y, ss.y);
            dist[j].x = n0; dist[j].y = n1;
            if (n0 > mv) { mv = n0; mi = tid + (2 * j) * 256; }     // strict >
            if (n1 > mv) { mv = n1; mi = tid + (2 * j + 1) * 256; } // ascending idx
        }
        // speculative winner-coord fetch: LDS pipe, overlaps the DPP ladder
        const float wx = xs[mi], wy = ys[mi], wz = zs[mi];
        // pack: dist bits high (dist>=0 so f32 bit order == value order),
        // (N-1-idx) low so u64-max tie-breaks to the SMALLEST index.
        const unsigned long long mykey =
            ((unsigned long long)__float_as_uint(mv) << 32) | (unsigned)(Nn - 1 - mi);
        const unsigned long long wkey = wave_max_u64(mykey);
        if (mykey == wkey) {                    // exactly one lane (keys unique)
            kbuf[s & 1][wid] = wkey;
            cbuf[s & 1][wid] = make_float4(wx, wy, wz, 0.0f);
        }
        __syncthreads();
        // all 6 LDS reads independent -> one latency window
        const ulonglong2 kv0 = *(const ulonglong2*)&kbuf[s & 1][0];
        const ulonglong2 kv1 = *(const ulonglong2*)&kbuf[s & 1][2];
        const float4 c0 = cbuf[s & 1][0];
        const float4 c1 = cbuf[s & 1][1];
        const float4 c2 = cbuf[s & 1][2];
        const float4 c3 = cbuf[s & 1][3];
        const bool b01 = kv0.y > kv0.x;
        const bool b23 = kv1.y > kv1.x;
        const unsigned long long k01 = b01 ? kv0.y : kv0.x;
        const unsigned long long k23 = b23 ? kv1.y : kv1.x;
        const float4 ca = b01 ? c1 : c0;
        const float4 cb = b23 ? c3 : c2;
        const float4 cw = (k23 > k01) ? cb : ca;
        cx = cw.x; cy = cw.y; cz = cw.z;
        if (tid == 0) {
            out_xyz[(size_t)(b * Sn + s) * 3 + 0] = cx;
            out_xyz[(size_t)(b * Sn + s) * 3 + 1] = cy;
            out_xyz[(size_t)(b * Sn + s) * 3 + 2] = cz;
        }
        // double-buffered kbuf/cbuf: no second barrier (pattern validated r9-r21)
    }
}

// ---- Wave-local ball query (validated r10-r21 ballot logic) ----------------
static __device__ __forceinline__ void wave_ball(const float* __restrict__ base,
                                                 float cx, float cy, float cz,
                                                 int lane, int* bslot) {
    int cnt = 0;
    int idx0 = -1;
    for (int chunk = 0; chunk < Nn / 64; ++chunk) {
        const int p = chunk * 64 + lane;
        const float d2 = sqdist(base[p], base[Nn + p], base[2 * Nn + p], cx, cy, cz);
        const bool in = (d2 <= 0.04f);             // f32(0.2*0.2)
        const unsigned long long m = __ballot(in);
        if (m != 0ull) {
            if (idx0 < 0) idx0 = chunk * 64 + __builtin_ctzll(m);
            const int rank = cnt + __popcll(m & ((1ull << lane) - 1ull));
            if (in && rank < Kn)
                bslot[rank] = p;                    // ascending by construction
            cnt += __popcll(m);
            if (cnt >= Kn) break;                   // wave-uniform
        }
    }
    if (lane < Kn && lane >= cnt)                   // pad with first index
        bslot[lane] = idx0;
}

// ---- Fused ball + bf16-MFMA conv + BN + ReLU + maxK (r20 text, validated) --
__global__ __launch_bounds__(512) void k_feat(const float* __restrict__ xyz,
                                              const float* __restrict__ out_xyz,
                                              const float* __restrict__ feat,
                                              const float* __restrict__ conv_w,
                                              const float* __restrict__ conv_b,
                                              const float* __restrict__ bn_g,
                                              const float* __restrict__ bn_b,
                                              const float* __restrict__ bn_m,
                                              const float* __restrict__ bn_v,
                                              float* __restrict__ out_feat) {
    __shared__ __align__(16) ushort A_lds[64][136];   // [(c,k)][f] 17.4 KB
    __shared__ __align__(16) ushort Wc[COUTn][40];    // [o][f_local] 20.5 KB
    __shared__ int bidx[8][Kn];
    const int tid = threadIdx.x;
    const int wave = tid >> 6, lane = tid & 63;
    const int b  = blockIdx.x & 15;                 // XCD-grouped batches
    const int c0 = (blockIdx.x >> 4) * 8;
    const int bs = b * Sn + c0 + wave;

    // ball query (wave-local)
    const float* base = xyz + (size_t)b * 3 * Nn;
    const float cx = out_xyz[(size_t)bs * 3 + 0];
    const float cy = out_xyz[(size_t)bs * 3 + 1];
    const float cz = out_xyz[(size_t)bs * 3 + 2];
    wave_ball(base, cx, cy, cz, lane, &bidx[wave][0]);
    __syncthreads();   // bidx visible to all waves (A staging reads it)

    // stage A (once): thread: row r=tid>>3 (=(c<<3)|k), f-range (tid&7)*16..+15
    const float* fb = feat + (size_t)b * CINn * Nn;
    {
        const int r = tid >> 3, fo = tid & 7;
        const int pt = bidx[r >> 3][r & 7];
        ushort us[16];
#pragma unroll
        for (int i = 0; i < 16; ++i)
            us[i] = f2bf(fb[(size_t)(fo * 16 + i) * Nn + pt]);
        *(ushort8*)&A_lds[r][fo * 16]     = *(const ushort8*)&us[0];
        *(ushort8*)&A_lds[r][fo * 16 + 8] = *(const ushort8*)&us[8];
    }

    // W chunk prefetch (ks=0): thread: o=tid>>1, f-half (tid&1)*16
    const int wo = tid >> 1, wfh = tid & 1;
    float4 stgW[4];
    {
        const float4* src = (const float4*)(conv_w + (size_t)wo * CINn + wfh * 16);
#pragma unroll
        for (int i = 0; i < 4; ++i) stgW[i] = src[i];
    }

    const int mt = wave & 3;
    const int obase = (wave >> 2) * 128;
    f32x4 acc[8];
#pragma unroll
    for (int t = 0; t < 8; ++t) acc[t] = (f32x4){0.f, 0.f, 0.f, 0.f};

    const int arow = mt * 16 + (lane & 15);
    const int kgrp = (lane >> 4) * 8;

#pragma unroll
    for (int ks = 0; ks < 4; ++ks) {
        // park W chunk (16 bf16 per thread -> 2 b128 writes)
        {
            ushort us[16];
#pragma unroll
            for (int i = 0; i < 4; ++i) {
                us[i * 4 + 0] = f2bf(stgW[i].x);
                us[i * 4 + 1] = f2bf(stgW[i].y);
                us[i * 4 + 2] = f2bf(stgW[i].z);
                us[i * 4 + 3] = f2bf(stgW[i].w);
            }
            *(ushort8*)&Wc[wo][wfh * 16]     = *(const ushort8*)&us[0];
            *(ushort8*)&Wc[wo][wfh * 16 + 8] = *(const ushort8*)&us[8];
        }
        __syncthreads();   // Wc[ks] ready (iter 0: A_lds too)
        // prefetch next W chunk
        if (ks < 3) {
            const float4* src = (const float4*)(conv_w + (size_t)wo * CINn +
                                                (ks + 1) * 32 + wfh * 16);
#pragma unroll
            for (int i = 0; i < 4; ++i) stgW[i] = src[i];
        }
        // compute: one A-frag (reused), 8 n-tiles
        const bf16x8 a = *(const bf16x8*)&A_lds[arow][ks * 32 + kgrp];
#pragma unroll
        for (int t = 0; t < 8; ++t) {
            const int o = obase + t * 16 + (lane & 15);
            const bf16x8 bb = *(const bf16x8*)&Wc[o][kgrp];
            acc[t] = __builtin_amdgcn_mfma_f32_16x16x32_bf16(a, bb, acc[t], 0, 0, 0);
        }
        __syncthreads();   // compute done before Wc overwrite
    }

    // epilogue: literal bias+BN+ReLU per (k,o), then max over k.
    const int half = lane >> 4;                 // 0,1: center A; 2,3: center B
#pragma unroll
    for (int t = 0; t < 8; ++t) {
        const int o = obase + t * 16 + (lane & 15);
        const float bias = conv_b[o];
        const float g = bn_g[o], be = bn_b[o], mn = bn_m[o], vr = bn_v[o];
        const float inv = sqrtf(vr + 1e-5f);
        float m4 = -3.402823466e+38f;
#pragma unroll
        for (int i = 0; i < 4; ++i) {
            float z = acc[t][i] + bias;
            float y = g * (z - mn) / inv + be;
            y = fmaxf(y, 0.0f);                 // ReLU before max, literal order
            m4 = fmaxf(m4, y);
        }
        const float mo = __shfl_xor(m4, 16);    // merge k 0-3 with k 4-7
        const float mx = fmaxf(m4, mo);
        if (half == 0)
            out_feat[(size_t)(b * Sn + c0 + mt * 2) * COUTn + o] = mx;
        else if (half == 2)
            out_feat[(size_t)(b * Sn + c0 + mt * 2 + 1) * COUTn + o] = mx;
    }
}

extern "C" void kernel_launch(void* const* d_in, const int* in_sizes, int n_in,
                              void* d_out, int out_size, void* d_ws, size_t ws_size,
                              hipStream_t stream) {
    const float* xyz    = (const float*)d_in[0];
    const float* feat   = (const float*)d_in[1];
    const float* conv_w = (const float*)d_in[2];
    const float* conv_b = (const float*)d_in[3];
    const float* bn_g   = (const float*)d_in[4];
    const float* bn_b   = (const float*)d_in[5];
    const float* bn_m   = (const float*)d_in[6];
    const float* bn_v   = (const float*)d_in[7];

    float* out_xyz  = (float*)d_out;
    float* out_feat = out_xyz + (size_t)Bn * Sn * 3;

    // no workspace usage
    k_fps <<<dim3(Bn),           dim3(256), 0, stream>>>(xyz, out_xyz);
    k_feat<<<dim3(Bn * Sn / 8),  dim3(512), 0, stream>>>(xyz, out_xyz, feat,
                                                         conv_w, conv_b,
                                                         bn_g, bn_b, bn_m, bn_v,
                                                         out_feat);
}

// Round 23
// 706.822 us; speedup vs baseline: 1.0972x; 1.0036x over previous
//
#include <hip/hip_runtime.h>
#include <hip/hip_bf16.h>
#include <stdint.h>

#define Bn   16
#define Nn   4096
#define Sn   1024
#define Kn   8
#define CINn 128
#define COUTn 256

typedef __attribute__((ext_vector_type(8))) short bf16x8;
typedef __attribute__((ext_vector_type(4))) float f32x4;
typedef unsigned short ushort;
typedef __attribute__((ext_vector_type(8))) unsigned short ushort8;

// Exact f32 squared distance, no FMA contraction: matches ((dx*dx+dy*dy)+dz*dz)
static __device__ __forceinline__ float sqdist(float ax, float ay, float az,
                                               float bx, float by, float bz) {
    float dx = __fsub_rn(ax, bx);
    float dy = __fsub_rn(ay, by);
    float dz = __fsub_rn(az, bz);
    return __fadd_rn(__fadd_rn(__fmul_rn(dx, dx), __fmul_rn(dy, dy)), __fmul_rn(dz, dz));
}

static __device__ __forceinline__ unsigned long long u64max(unsigned long long a,
                                                            unsigned long long b) {
    return a > b ? a : b;
}

// f32 -> bf16 bits, round-to-nearest-even (finite inputs)
static __device__ __forceinline__ ushort f2bf(float f) {
    unsigned x = __float_as_uint(f);
    unsigned r = x + 0x7FFFu + ((x >> 16) & 1u);
    return (ushort)(r >> 16);
}

// Wave-wide u64 max via DPP (VALU pipe, no LDS) — r14/r20-validated on HW.
template <int CTRL>
static __device__ __forceinline__ void dpp_max_level(int& lo, int& hi) {
    int olo = __builtin_amdgcn_update_dpp(lo, lo, CTRL, 0xF, 0xF, false);
    int ohi = __builtin_amdgcn_update_dpp(hi, hi, CTRL, 0xF, 0xF, false);
    unsigned long long o = ((unsigned long long)(unsigned)ohi << 32) | (unsigned)olo;
    unsigned long long k = ((unsigned long long)(unsigned)hi << 32) | (unsigned)lo;
    if (o > k) { lo = olo; hi = ohi; }
}

static __device__ __forceinline__ unsigned long long wave_max_u64(unsigned long long key) {
    int lo = (int)(unsigned)(key & 0xFFFFFFFFull);
    int hi = (int)(unsigned)(key >> 32);
    dpp_max_level<0x111>(lo, hi);   // row_shr:1
    dpp_max_level<0x112>(lo, hi);   // row_shr:2
    dpp_max_level<0x114>(lo, hi);   // row_shr:4
    dpp_max_level<0x118>(lo, hi);   // row_shr:8
    dpp_max_level<0x142>(lo, hi);   // row_bcast:15
    dpp_max_level<0x143>(lo, hi);   // row_bcast:31
    unsigned flo = (unsigned)__builtin_amdgcn_readlane(lo, 63);
    unsigned fhi = (unsigned)__builtin_amdgcn_readlane(hi, 63);
    return ((unsigned long long)fhi << 32) | flo;
}

// ---------------- Kernel: farthest point sampling (r20 text, measured 624us)
// Exact argmax/tie-break semantics (validated r6-r22 via output 0).
// 256 threads, 16 pts/thread. Per step: per-thread argmax -> u64 key ->
// DPP wave reduce (VALU) -> 4 wave-maxes in LDS (double-buffered, ONE
// barrier) -> broadcast read + 3 u64max -> next center.
// Empirical floor note: six structural variants (LDS butterfly 812,
// ds_swizzle 812, this 624, 8-wave 688, deferred-argmax 691,
// packed+coord-carry 644) establish this as the measured optimum; the
// workload is latency-bound on the serial reduce chain (HBM 0.01%,
// VALU 3.7% chip-wide = ~60% on the 16 active CUs).
__global__ __launch_bounds__(256) void k_fps(const float* __restrict__ xyz,
                                             float* __restrict__ out_xyz) {
    __shared__ __align__(16) float xs[Nn], ys[Nn], zs[Nn];
    __shared__ __align__(16) unsigned long long gbuf[2][4];
    const int b = blockIdx.x;
    const int tid = threadIdx.x;
    const int wid = tid >> 6, lane = tid & 63;
    const float* base = xyz + (size_t)b * 3 * Nn;
    for (int i = tid; i < Nn; i += 256) {
        xs[i] = base[i];
        ys[i] = base[Nn + i];
        zs[i] = base[2 * Nn + i];
    }
    __syncthreads();
    float px[16], py[16], pz[16], dist[16];
#pragma unroll
    for (int j = 0; j < 16; ++j) {
        int p = tid + j * 256;
        px[j] = xs[p]; py[j] = ys[p]; pz[j] = zs[p];
        dist[j] = 3.402823466e+38f;   // FLT_MAX, matches jnp.finfo(f32).max
    }
    int last = 0;
    if (tid == 0) {
        out_xyz[(size_t)(b * Sn) * 3 + 0] = xs[0];
        out_xyz[(size_t)(b * Sn) * 3 + 1] = ys[0];
        out_xyz[(size_t)(b * Sn) * 3 + 2] = zs[0];
    }
    for (int s = 1; s < Sn; ++s) {
        const float cx = xs[last], cy = ys[last], cz = zs[last];
        float mv = -1.0f; int mi = 0;
#pragma unroll
        for (int j = 0; j < 16; ++j) {
            float d = sqdist(px[j], py[j], pz[j], cx, cy, cz);
            float nd = fminf(dist[j], d);
            dist[j] = nd;
            if (nd > mv) { mv = nd; mi = tid + j * 256; }  // strict >: first-max wins
        }
        // pack: dist bits high (dist>=0 so f32 bit order == value order),
        // (N-1-idx) low so u64-max tie-breaks to the SMALLEST index.
        unsigned long long key =
            ((unsigned long long)__float_as_uint(mv) << 32) | (unsigned)(Nn - 1 - mi);
        key = wave_max_u64(key);            // all lanes hold wave max
        if (lane == 0) gbuf[s & 1][wid] = key;
        __syncthreads();
        const ulonglong2 g0 = *(const ulonglong2*)&gbuf[s & 1][0];
        const ulonglong2 g1 = *(const ulonglong2*)&gbuf[s & 1][2];
        key = u64max(u64max(g0.x, g0.y), u64max(g1.x, g1.y));
        const int nl = Nn - 1 - (int)(unsigned)(key & 0xFFFFFFFFull);
        if (tid == 0) {
            out_xyz[(size_t)(b * Sn + s) * 3 + 0] = xs[nl];
            out_xyz[(size_t)(b * Sn + s) * 3 + 1] = ys[nl];
            out_xyz[(size_t)(b * Sn + s) * 3 + 2] = zs[nl];
        }
        last = nl;
        // double-buffered gbuf: no second barrier (validated r9-r22)
    }
}

// ---- Wave-local ball query (validated r10-r22 ballot logic) ----------------
static __device__ __forceinline__ void wave_ball(const float* __restrict__ base,
                                                 float cx, float cy, float cz,
                                                 int lane, int* bslot) {
    int cnt = 0;
    int idx0 = -1;
    for (int chunk = 0; chunk < Nn / 64; ++chunk) {
        const int p = chunk * 64 + lane;
        const float d2 = sqdist(base[p], base[Nn + p], base[2 * Nn + p], cx, cy, cz);
        const bool in = (d2 <= 0.04f);             // f32(0.2*0.2)
        const unsigned long long m = __ballot(in);
        if (m != 0ull) {
            if (idx0 < 0) idx0 = chunk * 64 + __builtin_ctzll(m);
            const int rank = cnt + __popcll(m & ((1ull << lane) - 1ull));
            if (in && rank < Kn)
                bslot[rank] = p;                    // ascending by construction
            cnt += __popcll(m);
            if (cnt >= Kn) break;                   // wave-uniform
        }
    }
    if (lane < Kn && lane >= cnt)                   // pad with first index
        bslot[lane] = idx0;
}

// ---- Fused ball + bf16-MFMA conv + BN + ReLU + maxK (r20 text, validated) --
// Block: 512 thr = 8 waves = 8 centers. D[64=(c,k)][256 o] = A[64][128]·W^T.
// A staged once in LDS (bf16, stride 136 ush); W staged per-32-f chunk
// ([o][f_local] bf16, stride 40 ush), prefetched one chunk ahead.
// Fragments (mfma_f32_16x16x32_bf16): HW-validated r20 (absmax 0.03125).
__global__ __launch_bounds__(512) void k_feat(const float* __restrict__ xyz,
                                              const float* __restrict__ out_xyz,
                                              const float* __restrict__ feat,
                                              const float* __restrict__ conv_w,
                                              const float* __restrict__ conv_b,
                                              const float* __restrict__ bn_g,
                                              const float* __restrict__ bn_b,
                                              const float* __restrict__ bn_m,
                                              const float* __restrict__ bn_v,
                                              float* __restrict__ out_feat) {
    __shared__ __align__(16) ushort A_lds[64][136];   // [(c,k)][f] 17.4 KB
    __shared__ __align__(16) ushort Wc[COUTn][40];    // [o][f_local] 20.5 KB
    __shared__ int bidx[8][Kn];
    const int tid = threadIdx.x;
    const int wave = tid >> 6, lane = tid & 63;
    const int b  = blockIdx.x & 15;                 // XCD-grouped batches
    const int c0 = (blockIdx.x >> 4) * 8;
    const int bs = b * Sn + c0 + wave;

    // ball query (wave-local)
    const float* base = xyz + (size_t)b * 3 * Nn;
    const float cx = out_xyz[(size_t)bs * 3 + 0];
    const float cy = out_xyz[(size_t)bs * 3 + 1];
    const float cz = out_xyz[(size_t)bs * 3 + 2];
    wave_ball(base, cx, cy, cz, lane, &bidx[wave][0]);
    __syncthreads();   // bidx visible to all waves (A staging reads it)

    // stage A (once): thread: row r=tid>>3 (=(c<<3)|k), f-range (tid&7)*16..+15
    const float* fb = feat + (size_t)b * CINn * Nn;
    {
        const int r = tid >> 3, fo = tid & 7;
        const int pt = bidx[r >> 3][r & 7];
        ushort us[16];
#pragma unroll
        for (int i = 0; i < 16; ++i)
            us[i] = f2bf(fb[(size_t)(fo * 16 + i) * Nn + pt]);
        *(ushort8*)&A_lds[r][fo * 16]     = *(const ushort8*)&us[0];
        *(ushort8*)&A_lds[r][fo * 16 + 8] = *(const ushort8*)&us[8];
    }

    // W chunk prefetch (ks=0): thread: o=tid>>1, f-half (tid&1)*16
    const int wo = tid >> 1, wfh = tid & 1;
    float4 stgW[4];
    {
        const float4* src = (const float4*)(conv_w + (size_t)wo * CINn + wfh * 16);
#pragma unroll
        for (int i = 0; i < 4; ++i) stgW[i] = src[i];
    }

    const int mt = wave & 3;
    const int obase = (wave >> 2) * 128;
    f32x4 acc[8];
#pragma unroll
    for (int t = 0; t < 8; ++t) acc[t] = (f32x4){0.f, 0.f, 0.f, 0.f};

    const int arow = mt * 16 + (lane & 15);
    const int kgrp = (lane >> 4) * 8;

#pragma unroll
    for (int ks = 0; ks < 4; ++ks) {
        // park W chunk (16 bf16 per thread -> 2 b128 writes)
        {
            ushort us[16];
#pragma unroll
            for (int i = 0; i < 4; ++i) {
                us[i * 4 + 0] = f2bf(stgW[i].x);
                us[i * 4 + 1] = f2bf(stgW[i].y);
                us[i * 4 + 2] = f2bf(stgW[i].z);
                us[i * 4 + 3] = f2bf(stgW[i].w);
            }
            *(ushort8*)&Wc[wo][wfh * 16]     = *(const ushort8*)&us[0];
            *(ushort8*)&Wc[wo][wfh * 16 + 8] = *(const ushort8*)&us[8];
        }
        __syncthreads();   // Wc[ks] ready (iter 0: A_lds too)
        // prefetch next W chunk
        if (ks < 3) {
            const float4* src = (const float4*)(conv_w + (size_t)wo * CINn +
                                                (ks + 1) * 32 + wfh * 16);
#pragma unroll
            for (int i = 0; i < 4; ++i) stgW[i] = src[i];
        }
        // compute: one A-frag (reused), 8 n-tiles
        const bf16x8 a = *(const bf16x8*)&A_lds[arow][ks * 32 + kgrp];
#pragma unroll
        for (int t = 0; t < 8; ++t) {
            const int o = obase + t * 16 + (lane & 15);
            const bf16x8 bb = *(const bf16x8*)&Wc[o][kgrp];
            acc[t] = __builtin_amdgcn_mfma_f32_16x16x32_bf16(a, bb, acc[t], 0, 0, 0);
        }
        __syncthreads();   // compute done before Wc overwrite
    }

    // epilogue: literal bias+BN+ReLU per (k,o), then max over k.
    const int half = lane >> 4;                 // 0,1: center A; 2,3: center B
#pragma unroll
    for (int t = 0; t < 8; ++t) {
        const int o = obase + t * 16 + (lane & 15);
        const float bias = conv_b[o];
        const float g = bn_g[o], be = bn_b[o], mn = bn_m[o], vr = bn_v[o];
        const float inv = sqrtf(vr + 1e-5f);
        float m4 = -3.402823466e+38f;
#pragma unroll
        for (int i = 0; i < 4; ++i) {
            float z = acc[t][i] + bias;
            float y = g * (z - mn) / inv + be;
            y = fmaxf(y, 0.0f);                 // ReLU before max, literal order
            m4 = fmaxf(m4, y);
        }
        const float mo = __shfl_xor(m4, 16);    // merge k 0-3 with k 4-7
        const float mx = fmaxf(m4, mo);
        if (half == 0)
            out_feat[(size_t)(b * Sn + c0 + mt * 2) * COUTn + o] = mx;
        else if (half == 2)
            out_feat[(size_t)(b * Sn + c0 + mt * 2 + 1) * COUTn + o] = mx;
    }
}

extern "C" void kernel_launch(void* const* d_in, const int* in_sizes, int n_in,
                              void* d_out, int out_size, void* d_ws, size_t ws_size,
                              hipStream_t stream) {
    const float* xyz    = (const float*)d_in[0];
    const float* feat   = (const float*)d_in[1];
    const float* conv_w = (const float*)d_in[2];
    const float* conv_b = (const float*)d_in[3];
    const float* bn_g   = (const float*)d_in[4];
    const float* bn_b   = (const float*)d_in[5];
    const float* bn_m   = (const float*)d_in[6];
    const float* bn_v   = (const float*)d_in[7];

    float* out_xyz  = (float*)d_out;
    float* out_feat = out_xyz + (size_t)Bn * Sn * 3;

    // no workspace usage
    k_fps <<<dim3(Bn),           dim3(256), 0, stream>>>(xyz, out_xyz);
    k_feat<<<dim3(Bn * Sn / 8),  dim3(512), 0, stream>>>(xyz, out_xyz, feat,
                                                         conv_w, conv_b,
                                                         bn_g, bn_b, bn_m, bn_v,
                                                         out_feat);
}

// Round 24
// 691.510 us; speedup vs baseline: 1.1215x; 1.0221x over previous
//
#include <hip/hip_runtime.h>
#include <hip/hip_bf16.h>
#include <stdint.h>

#define Bn   16
#define Nn   4096
#define Sn   1024
#define Kn   8
#define CINn 128
#define COUTn 256

#define NFPS 16
#define NBLK 240      // 16 fps + 224 feat; <= 256 CUs at 1 block/CU => all co-resident

typedef __attribute__((ext_vector_type(8))) short bf16x8;
typedef __attribute__((ext_vector_type(4))) float f32x4;
typedef unsigned short ushort;
typedef __attribute__((ext_vector_type(8))) unsigned short ushort8;

#define ATOM_ST_F32(p, v) __hip_atomic_store((p), (v), __ATOMIC_RELAXED, __HIP_MEMORY_SCOPE_AGENT)
#define ATOM_LD_F32(p)    __hip_atomic_load((p), __ATOMIC_RELAXED, __HIP_MEMORY_SCOPE_AGENT)
#define ATOM_ST_I32(p, v) __hip_atomic_store((p), (v), __ATOMIC_RELAXED, __HIP_MEMORY_SCOPE_AGENT)
#define ATOM_LD_I32(p)    __hip_atomic_load((p), __ATOMIC_RELAXED, __HIP_MEMORY_SCOPE_AGENT)

// Exact f32 squared distance, no FMA contraction: matches ((dx*dx+dy*dy)+dz*dz)
static __device__ __forceinline__ float sqdist(float ax, float ay, float az,
                                               float bx, float by, float bz) {
    float dx = __fsub_rn(ax, bx);
    float dy = __fsub_rn(ay, by);
    float dz = __fsub_rn(az, bz);
    return __fadd_rn(__fadd_rn(__fmul_rn(dx, dx), __fmul_rn(dy, dy)), __fmul_rn(dz, dz));
}

static __device__ __forceinline__ unsigned long long u64max(unsigned long long a,
                                                            unsigned long long b) {
    return a > b ? a : b;
}

// f32 -> bf16 bits, round-to-nearest-even (finite inputs)
static __device__ __forceinline__ ushort f2bf(float f) {
    unsigned x = __float_as_uint(f);
    unsigned r = x + 0x7FFFu + ((x >> 16) & 1u);
    return (ushort)(r >> 16);
}

// Wave-wide u64 max via DPP (VALU pipe, no LDS) — r14/r20-validated on HW.
template <int CTRL>
static __device__ __forceinline__ void dpp_max_level(int& lo, int& hi) {
    int olo = __builtin_amdgcn_update_dpp(lo, lo, CTRL, 0xF, 0xF, false);
    int ohi = __builtin_amdgcn_update_dpp(hi, hi, CTRL, 0xF, 0xF, false);
    unsigned long long o = ((unsigned long long)(unsigned)ohi << 32) | (unsigned)olo;
    unsigned long long k = ((unsigned long long)(unsigned)hi << 32) | (unsigned)lo;
    if (o > k) { lo = olo; hi = ohi; }
}

static __device__ __forceinline__ unsigned long long wave_max_u64(unsigned long long key) {
    int lo = (int)(unsigned)(key & 0xFFFFFFFFull);
    int hi = (int)(unsigned)(key >> 32);
    dpp_max_level<0x111>(lo, hi);   // row_shr:1
    dpp_max_level<0x112>(lo, hi);   // row_shr:2
    dpp_max_level<0x114>(lo, hi);   // row_shr:4
    dpp_max_level<0x118>(lo, hi);   // row_shr:8
    dpp_max_level<0x142>(lo, hi);   // row_bcast:15
    dpp_max_level<0x143>(lo, hi);   // row_bcast:31
    unsigned flo = (unsigned)__builtin_amdgcn_readlane(lo, 63);
    unsigned fhi = (unsigned)__builtin_amdgcn_readlane(hi, 63);
    return ((unsigned long long)fhi << 32) | flo;
}

// ---- Wave-local ball query (validated r10-r23 ballot logic) ----------------
static __device__ __forceinline__ void wave_ball(const float* __restrict__ base,
                                                 float cx, float cy, float cz,
                                                 int lane, int* bslot) {
    int cnt = 0;
    int idx0 = -1;
    for (int chunk = 0; chunk < Nn / 64; ++chunk) {
        const int p = chunk * 64 + lane;
        const float d2 = sqdist(base[p], base[Nn + p], base[2 * Nn + p], cx, cy, cz);
        const bool in = (d2 <= 0.04f);             // f32(0.2*0.2)
        const unsigned long long m = __ballot(in);
        if (m != 0ull) {
            if (idx0 < 0) idx0 = chunk * 64 + __builtin_ctzll(m);
            const int rank = cnt + __popcll(m & ((1ull << lane) - 1ull));
            if (in && rank < Kn)
                bslot[rank] = p;                    // ascending by construction
            cnt += __popcll(m);
            if (cnt >= Kn) break;                   // wave-uniform
        }
    }
    if (lane < Kn && lane >= cnt)                   // pad with first index
        bslot[lane] = idx0;
}

// ---- Fused producer-consumer kernel ----------------------------------------
// Blocks 0..15: FPS for batch b (r20 text, measured 624us) — centers published
// via agent-scope atomic stores; progress[b] published every 64 steps after a
// vmcnt(0) drain. Threads 256-511 run a barrier-matching idle loop.
// Blocks 16..239: feat tiles (r20 bf16-MFMA text), grid-striding 2048 tiles;
// per tile spin on progress[b] >= c0+8, centers read via agent-scope loads.
// 84KB static LDS forces 1 block/CU: 240 blocks <= 256 CUs => all co-resident
// (capacity guarantee, no dispatch-order assumption) and fps CUs exclusive.
__global__ __launch_bounds__(512, 2) void k_fused(
        const float* __restrict__ xyz,
        const float* __restrict__ feat,
        const float* __restrict__ conv_w,
        const float* __restrict__ conv_b,
        const float* __restrict__ bn_g,
        const float* __restrict__ bn_b,
        const float* __restrict__ bn_m,
        const float* __restrict__ bn_v,
        float* __restrict__ out_xyz,
        float* __restrict__ out_feat,
        int* __restrict__ progress) {
    __shared__ __align__(16) char shm[86016];   // 84KB -> 1 block/CU
    const int tid = threadIdx.x;
    const int bid = blockIdx.x;

    if (bid < NFPS) {
        // ================= FPS role (r20 kernel, validated) =================
        const int b = bid;
        if (tid >= 256) {
            // barrier-matching idle loop: 1 staging + 1023 step barriers
            for (int s = 0; s < Sn; ++s) __syncthreads();
            return;
        }
        float* xs = (float*)shm;
        float* ys = xs + Nn;
        float* zs = ys + Nn;
        unsigned long long (*gbuf)[4] =
            (unsigned long long(*)[4])(shm + 3 * Nn * sizeof(float));
        const int wid = tid >> 6, lane = tid & 63;
        const float* base = xyz + (size_t)b * 3 * Nn;
        for (int i = tid; i < Nn; i += 256) {
            xs[i] = base[i];
            ys[i] = base[Nn + i];
            zs[i] = base[2 * Nn + i];
        }
        __syncthreads();
        float px[16], py[16], pz[16], dist[16];
#pragma unroll
        for (int j = 0; j < 16; ++j) {
            int p = tid + j * 256;
            px[j] = xs[p]; py[j] = ys[p]; pz[j] = zs[p];
            dist[j] = 3.402823466e+38f;   // FLT_MAX
        }
        int last = 0;
        if (tid == 0) {
            ATOM_ST_F32(&out_xyz[(size_t)(b * Sn) * 3 + 0], xs[0]);
            ATOM_ST_F32(&out_xyz[(size_t)(b * Sn) * 3 + 1], ys[0]);
            ATOM_ST_F32(&out_xyz[(size_t)(b * Sn) * 3 + 2], zs[0]);
        }
        for (int s = 1; s < Sn; ++s) {
            const float cx = xs[last], cy = ys[last], cz = zs[last];
            float mv = -1.0f; int mi = 0;
#pragma unroll
            for (int j = 0; j < 16; ++j) {
                float d = sqdist(px[j], py[j], pz[j], cx, cy, cz);
                float nd = fminf(dist[j], d);
                dist[j] = nd;
                if (nd > mv) { mv = nd; mi = tid + j * 256; }  // strict >
            }
            unsigned long long key =
                ((unsigned long long)__float_as_uint(mv) << 32) |
                (unsigned)(Nn - 1 - mi);
            key = wave_max_u64(key);
            if (lane == 0) gbuf[s & 1][wid] = key;
            __syncthreads();
            const ulonglong2 g0 = *(const ulonglong2*)&gbuf[s & 1][0];
            const ulonglong2 g1 = *(const ulonglong2*)&gbuf[s & 1][2];
            key = u64max(u64max(g0.x, g0.y), u64max(g1.x, g1.y));
            const int nl = Nn - 1 - (int)(unsigned)(key & 0xFFFFFFFFull);
            if (tid == 0) {
                ATOM_ST_F32(&out_xyz[(size_t)(b * Sn + s) * 3 + 0], xs[nl]);
                ATOM_ST_F32(&out_xyz[(size_t)(b * Sn + s) * 3 + 1], ys[nl]);
                ATOM_ST_F32(&out_xyz[(size_t)(b * Sn + s) * 3 + 2], zs[nl]);
                if ((s & 63) == 63) {
                    // drain coherent stores, then publish (release ordering by hand)
                    asm volatile("s_waitcnt vmcnt(0)" ::: "memory");
                    ATOM_ST_I32(progress + b, s + 1);
                }
            }
            last = nl;
            // double-buffered gbuf: no second barrier (validated r9-r23)
        }
        return;
    }

    // ================= feat role (r20 kernel body, validated) ===============
    ushort (*A_lds)[136] = (ushort(*)[136])shm;                    // 17408 B
    ushort (*Wc)[40]     = (ushort(*)[40])(shm + 17408);           // 20480 B
    int (*bidx)[Kn]      = (int(*)[Kn])(shm + 17408 + 20480);      //   256 B
    const int wave = tid >> 6, lane = tid & 63;

    for (int t = bid - NFPS; t < Bn * Sn / 8; t += NBLK - NFPS) {
        const int b  = t & 15;
        const int c0 = (t >> 4) * 8;
        const int bs = b * Sn + c0 + wave;

        // wait until this tile's 8 centers are published
        if (tid == 0) {
            while (ATOM_LD_I32(progress + b) < c0 + 8)
                __builtin_amdgcn_s_sleep(8);
        }
        __syncthreads();

        // centers via agent-scope coherent loads (bypass non-coherent caches)
        const float cx = ATOM_LD_F32(&out_xyz[(size_t)bs * 3 + 0]);
        const float cy = ATOM_LD_F32(&out_xyz[(size_t)bs * 3 + 1]);
        const float cz = ATOM_LD_F32(&out_xyz[(size_t)bs * 3 + 2]);

        const float* base = xyz + (size_t)b * 3 * Nn;
        wave_ball(base, cx, cy, cz, lane, &bidx[wave][0]);
        __syncthreads();   // bidx visible to all waves (A staging reads it)

        // stage A: row r=tid>>3 (=(c<<3)|k), f-range (tid&7)*16..+15
        const float* fb = feat + (size_t)b * CINn * Nn;
        {
            const int r = tid >> 3, fo = tid & 7;
            const int pt = bidx[r >> 3][r & 7];
            ushort us[16];
#pragma unroll
            for (int i = 0; i < 16; ++i)
                us[i] = f2bf(fb[(size_t)(fo * 16 + i) * Nn + pt]);
            *(ushort8*)&A_lds[r][fo * 16]     = *(const ushort8*)&us[0];
            *(ushort8*)&A_lds[r][fo * 16 + 8] = *(const ushort8*)&us[8];
        }

        // W chunk prefetch (ks=0): thread: o=tid>>1, f-half (tid&1)*16
        const int wo = tid >> 1, wfh = tid & 1;
        float4 stgW[4];
        {
            const float4* src = (const float4*)(conv_w + (size_t)wo * CINn + wfh * 16);
#pragma unroll
            for (int i = 0; i < 4; ++i) stgW[i] = src[i];
        }

        const int mt = wave & 3;
        const int obase = (wave >> 2) * 128;
        f32x4 acc[8];
#pragma unroll
        for (int tt = 0; tt < 8; ++tt) acc[tt] = (f32x4){0.f, 0.f, 0.f, 0.f};

        const int arow = mt * 16 + (lane & 15);
        const int kgrp = (lane >> 4) * 8;

#pragma unroll
        for (int ks = 0; ks < 4; ++ks) {
            // park W chunk (16 bf16 per thread -> 2 b128 writes)
            {
                ushort us[16];
#pragma unroll
                for (int i = 0; i < 4; ++i) {
                    us[i * 4 + 0] = f2bf(stgW[i].x);
                    us[i * 4 + 1] = f2bf(stgW[i].y);
                    us[i * 4 + 2] = f2bf(stgW[i].z);
                    us[i * 4 + 3] = f2bf(stgW[i].w);
                }
                *(ushort8*)&Wc[wo][wfh * 16]     = *(const ushort8*)&us[0];
                *(ushort8*)&Wc[wo][wfh * 16 + 8] = *(const ushort8*)&us[8];
            }
            __syncthreads();   // Wc[ks] ready (iter 0: A_lds too)
            if (ks < 3) {
                const float4* src = (const float4*)(conv_w + (size_t)wo * CINn +
                                                    (ks + 1) * 32 + wfh * 16);
#pragma unroll
                for (int i = 0; i < 4; ++i) stgW[i] = src[i];
            }
            const bf16x8 a = *(const bf16x8*)&A_lds[arow][ks * 32 + kgrp];
#pragma unroll
            for (int tt = 0; tt < 8; ++tt) {
                const int o = obase + tt * 16 + (lane & 15);
                const bf16x8 bb = *(const bf16x8*)&Wc[o][kgrp];
                acc[tt] = __builtin_amdgcn_mfma_f32_16x16x32_bf16(a, bb, acc[tt], 0, 0, 0);
            }
            __syncthreads();   // compute done before Wc overwrite
        }

        // epilogue: literal bias+BN+ReLU per (k,o), then max over k.
        const int half = lane >> 4;
#pragma unroll
        for (int tt = 0; tt < 8; ++tt) {
            const int o = obase + tt * 16 + (lane & 15);
            const float bias = conv_b[o];
            const float g = bn_g[o], be = bn_b[o], mn = bn_m[o], vr = bn_v[o];
            const float inv = sqrtf(vr + 1e-5f);
            float m4 = -3.402823466e+38f;
#pragma unroll
            for (int i = 0; i < 4; ++i) {
                float z = acc[tt][i] + bias;
                float y = g * (z - mn) / inv + be;
                y = fmaxf(y, 0.0f);             // ReLU before max, literal order
                m4 = fmaxf(m4, y);
            }
            const float mo = __shfl_xor(m4, 16);
            const float mx = fmaxf(m4, mo);
            if (half == 0)
                out_feat[(size_t)(b * Sn + c0 + mt * 2) * COUTn + o] = mx;
            else if (half == 2)
                out_feat[(size_t)(b * Sn + c0 + mt * 2 + 1) * COUTn + o] = mx;
        }
    }
}

extern "C" void kernel_launch(void* const* d_in, const int* in_sizes, int n_in,
                              void* d_out, int out_size, void* d_ws, size_t ws_size,
                              hipStream_t stream) {
    const float* xyz    = (const float*)d_in[0];
    const float* feat   = (const float*)d_in[1];
    const float* conv_w = (const float*)d_in[2];
    const float* conv_b = (const float*)d_in[3];
    const float* bn_g   = (const float*)d_in[4];
    const float* bn_b   = (const float*)d_in[5];
    const float* bn_m   = (const float*)d_in[6];
    const float* bn_v   = (const float*)d_in[7];

    float* out_xyz  = (float*)d_out;
    float* out_feat = out_xyz + (size_t)Bn * Sn * 3;

    int* progress = (int*)d_ws;   // 64 B, re-zeroed every launch (graph-captured)
    hipMemsetAsync(progress, 0, Bn * sizeof(int), stream);

    k_fused<<<dim3(NBLK), dim3(512), 0, stream>>>(xyz, feat, conv_w, conv_b,
                                                  bn_g, bn_b, bn_m, bn_v,
                                                  out_xyz, out_feat, progress);
}